// Round 5
// baseline (418.226 us; speedup 1.0000x reference)
//
#include <hip/hip_runtime.h>

// Problem: out[j] = max(x[j], -c[rank_j]) per row, rank_j = position of j in
// stable ascending sort of key = x*rho.  B=4096 rows, P=8192.
//
// R5: residency + barrier-granularity attack. R4 showed the idle gap is NOT
// one serial loop: it's ~12 barriers/row over 16-wave blocks with only 2
// independent rows/CU. Changes:
//  - BDIM 512 (EPT=16): LDS ~49KB -> 3 blocks/CU (24 waves), THREE independent
//    rows hide each other's barriers; barriers sync 8 waves not 16.
//  - Register diet for 6 waves/SIMD (VGPR<=85): persist only key[]+bin2[];
//    x re-read in epilogue (L2-hot), mine recomputed. __launch_bounds__(512,6).
//  - Scan drops a barrier: all threads redundantly reduce the 8 wave totals
//    (broadcast LDS reads) instead of wave0-pass + barrier.
//  - Phase 7 window 8 -> 4 slots (covers 98% of elements, Poisson(1)); exact
//    fallback for the 2% tail.

constexpr int P_LEN  = 8192;            // row length == #bins (13 bits)
constexpr int BDIM   = 512;             // threads per block
constexpr int EPT    = P_LEN / BDIM;    // 16 elements per thread
constexpr int NW     = BDIM / 64;       // 8 waves
constexpr int CWORDS = P_LEN / 2;       // 4096 packed counter words
constexpr int WPT    = CWORDS / BDIM;   // 8 packed words per thread
constexpr int WIN    = 4;               // rank fast-path window

__device__ __forceinline__ unsigned fkey(float f) {
    unsigned u = __float_as_uint(f);
    // order-preserving map: negatives -> ~u, positives -> u|sign
    return (u & 0x80000000u) ? ~u : (u | 0x80000000u);
}

// packed-counter helpers: bin v in [0,8192) lives in half (v>>12) of word (v&4095)
__device__ __forceinline__ unsigned pk_word(unsigned v) { return v & (CWORDS - 1u); }
__device__ __forceinline__ unsigned pk_inc(unsigned v)  { return (v & (unsigned)CWORDS) ? 0x10000u : 1u; }
__device__ __forceinline__ unsigned pk_get(unsigned w, unsigned v) { return (w >> ((v >> 12) << 4)) & 0xFFFFu; }
// ushort index of bin v's half (little-endian: lo half = 2*word, hi = 2*word+1)
__device__ __forceinline__ unsigned pk_us(unsigned v)   { return ((v & (CWORDS - 1u)) << 1) | (v >> 12); }

// In-place exclusive scan of 8192 packed counts. After: word w holds
// (startLo(w)) | (startHi(w) << 16). One barrier inside (plus trailing one).
__device__ __forceinline__ void scan_packed(unsigned* cnt, unsigned* wt,
                                            int t, int lane, int wid)
{
    uint4 ca = ((const uint4*)cnt)[t * 2];
    uint4 cb = ((const uint4*)cnt)[t * 2 + 1];
    unsigned p[WPT] = {ca.x, ca.y, ca.z, ca.w, cb.x, cb.y, cb.z, cb.w};
    unsigned pre[WPT];
    unsigned s = 0;
#pragma unroll
    for (int i = 0; i < WPT; ++i) { pre[i] = s; s += p[i]; }   // packed local prefix

    unsigned incl = s;
#pragma unroll
    for (int d = 1; d < 64; d <<= 1) {
        unsigned v = __shfl_up(incl, d, 64);
        if (lane >= d) incl += v;
    }
    if (lane == 63) wt[wid] = incl;                  // packed wave totals
    __syncthreads();
    // every thread reduces the NW totals itself (broadcast reads, no 2nd barrier)
    unsigned waveBase = 0, tot = 0;
#pragma unroll
    for (int w = 0; w < NW; ++w) {
        const unsigned v = wt[w];
        waveBase += (w < wid) ? v : 0u;
        tot += v;
    }
    const unsigned base = waveBase + (incl - s);     // packed exclusive prefix
    const unsigned totL = tot & 0xFFFFu;             // #elements in lo-half bins
    unsigned q[WPT];
#pragma unroll
    for (int i = 0; i < WPT; ++i) {
        const unsigned qi = base + pre[i];
        q[i] = (qi & 0xFFFFu) | ((totL + (qi >> 16)) << 16);
    }
    ((uint4*)cnt)[t * 2]     = make_uint4(q[0], q[1], q[2], q[3]);
    ((uint4*)cnt)[t * 2 + 1] = make_uint4(q[4], q[5], q[6], q[7]);
    __syncthreads();
}

__global__ __launch_bounds__(BDIM, 6)   // 6 waves/EU -> 3 blocks/CU; VGPR <= 85
void qp_rank_kernel(const float* __restrict__ x,
                    const float* __restrict__ rho,
                    const float* __restrict__ c,
                    float* __restrict__ out)
{
    __shared__ unsigned cnt[CWORDS];        // 16 KB packed counters/starts/ends
    __shared__ unsigned mem[P_LEN + WIN];   // 32 KB members + window pad
    __shared__ unsigned wt[NW];             // scan scratch

    const int row  = blockIdx.x;
    const int t    = threadIdx.x;
    const int j0   = t * EPT;
    const int lane = t & 63;
    const int wid  = t >> 6;

    const float* __restrict__ xr   = x   + (size_t)row * P_LEN;
    const float* __restrict__ rr   = rho + (size_t)row * P_LEN;
    float*       __restrict__ outr = out + (size_t)row * P_LEN;
    const unsigned short* usview = (const unsigned short*)cnt;

    // ---- phase 0: zero packed histogram (2 uint4 per thread) ----
    const uint4 z4 = make_uint4(0u, 0u, 0u, 0u);
    ((uint4*)cnt)[t * 2]     = z4;
    ((uint4*)cnt)[t * 2 + 1] = z4;
    __syncthreads();

    // ---- phase 1: load, keys, level-1 histogram (top 13 bits) ----
    unsigned key[EPT];
    {
        float4 xv[EPT / 4], rv[EPT / 4];
#pragma unroll
        for (int v = 0; v < EPT / 4; ++v) {
            xv[v] = ((const float4*)(xr + j0))[v];
            rv[v] = ((const float4*)(rr + j0))[v];
        }
#pragma unroll
        for (int v = 0; v < EPT / 4; ++v) {
            key[v * 4 + 0] = fkey(xv[v].x * rv[v].x);
            key[v * 4 + 1] = fkey(xv[v].y * rv[v].y);
            key[v * 4 + 2] = fkey(xv[v].z * rv[v].z);
            key[v * 4 + 3] = fkey(xv[v].w * rv[v].w);
        }
    }
#pragma unroll
    for (int k = 0; k < EPT; ++k) {
        const unsigned b = key[k] >> 19;
        atomicAdd(&cnt[pk_word(b)], pk_inc(b));
    }
    __syncthreads();

    // ---- phase 2: scan1 -> packed starts of level-1 bins ----
    scan_packed(cnt, wt, t, lane, wid);

    // ---- phase 3: adaptive refinement: bin2 = s_b + (sz_b * r) >> 13 ----
    // r = next 13 key bits. Monotone re-binning onto position space [0,8192);
    // same bin2 implies same top-13 key bits.
    unsigned bin2[EPT];
#pragma unroll
    for (int k = 0; k < EPT; ++k) {
        const unsigned b   = key[k] >> 19;
        const unsigned s_b = usview[pk_us(b)];
        const unsigned e_b = (b == (unsigned)(P_LEN - 1)) ? (unsigned)P_LEN
                                                          : usview[pk_us(b + 1)];
        const unsigned sz  = e_b - s_b;
        const unsigned r   = (key[k] >> 6) & 0x1FFFu;
        bin2[k] = s_b + ((sz * r) >> 13);
    }
    __syncthreads();   // all starts1 reads complete before re-zero

    // ---- phase 4: re-zero, level-2 histogram (near-conflict-free) ----
    ((uint4*)cnt)[t * 2]     = z4;
    ((uint4*)cnt)[t * 2 + 1] = z4;
    __syncthreads();
#pragma unroll
    for (int k = 0; k < EPT; ++k)
        atomicAdd(&cnt[pk_word(bin2[k])], pk_inc(bin2[k]));
    __syncthreads();

    // ---- phase 5: scan2 -> packed starts of level-2 bins ----
    scan_packed(cnt, wt, t, lane, wid);

    // ---- phase 6: scatter residuals; cnt halves become bin2 ends ----
#pragma unroll
    for (int k = 0; k < EPT; ++k) {
        const unsigned b2  = bin2[k];
        const unsigned old = atomicAdd(&cnt[pk_word(b2)], pk_inc(b2));
        mem[pk_get(old, b2)] = (key[k] << 13) | (unsigned)(j0 + k);
    }
    __syncthreads();

    // ---- phase 7+8 fused per 4-element group (limits live registers) ----
#pragma unroll
    for (int g = 0; g < EPT / 4; ++g) {
        const float4 xg = ((const float4*)(xr + j0))[g];   // L2/L3-hot re-read
        unsigned rk[4];
#pragma unroll
        for (int kk = 0; kk < 4; ++kk) {
            const int k = g * 4 + kk;
            const unsigned b2 = bin2[k];
            const unsigned lo = (b2 == 0u) ? 0u : usview[pk_us(b2 - 1)];
            const unsigned hi = usview[pk_us(b2)];
            const unsigned m  = (key[k] << 13) | (unsigned)(j0 + k);
            const unsigned* mp = mem + lo;     // 4 consecutive reads -> ds_read2
            unsigned w[WIN];
#pragma unroll
            for (int i = 0; i < WIN; ++i) w[i] = mp[i];
            unsigned r = lo;
#pragma unroll
            for (int i = 0; i < WIN; ++i)
                r += ((lo + (unsigned)i < hi) && (w[i] < m)) ? 1u : 0u;
            unsigned q = lo + WIN;             // rare exact fallback (~2%)
#pragma unroll 1
            while (q < hi) { r += (mem[q] < m) ? 1u : 0u; ++q; }
            rk[kk] = r;
        }
        float4 res;
        res.x = fmaxf(xg.x, -c[rk[0]]);
        res.y = fmaxf(xg.y, -c[rk[1]]);
        res.z = fmaxf(xg.z, -c[rk[2]]);
        res.w = fmaxf(xg.w, -c[rk[3]]);
        ((float4*)(outr + j0))[g] = res;
    }
}

extern "C" void kernel_launch(void* const* d_in, const int* in_sizes, int n_in,
                              void* d_out, int out_size, void* d_ws, size_t ws_size,
                              hipStream_t stream) {
    const float* x   = (const float*)d_in[0];
    const float* rho = (const float*)d_in[1];
    const float* c   = (const float*)d_in[2];
    float* out = (float*)d_out;
    const int rows = in_sizes[0] / P_LEN;   // 4096
    qp_rank_kernel<<<rows, BDIM, 0, stream>>>(x, rho, c, out);
}